// Round 8
// baseline (631.630 us; speedup 1.0000x reference)
//
#include <hip/hip_runtime.h>
#include <math.h>
#include <stdint.h>

#define NEG 0.2f
#define CSHIFT 8
#define MAXNB 512          // supports n <= 131072 (17-bit src pack)
#define CHUNK 8192

// ============================ node transform ============================

__global__ __launch_bounds__(256) void k1_node(const float* __restrict__ x,
    const float* __restrict__ W1, const float* __restrict__ a1s, const float* __restrict__ a1d,
    float* __restrict__ h1, float* __restrict__ as1, float* __restrict__ ad1, int n)
{
    __shared__ float wt[8 * 128];
    __shared__ float av[16];
    for (int i = threadIdx.x; i < 1024; i += 256) {
        int r = i >> 3, k = i & 7;
        wt[k * 128 + r] = W1[i];
    }
    if (threadIdx.x < 8)        av[threadIdx.x] = a1s[threadIdx.x];
    else if (threadIdx.x < 16)  av[threadIdx.x] = a1d[threadIdx.x - 8];
    __syncthreads();

    int lane = threadIdx.x & 31;
    int node = blockIdx.x * 8 + (threadIdx.x >> 5);
    if (node >= n) return;

    float4 xv = ((const float4*)(x + (size_t)node * 128))[lane];
    float p[8];
#pragma unroll
    for (int k = 0; k < 8; ++k) {
        float4 wv = ((const float4*)(wt + k * 128))[lane];
        p[k] = xv.x * wv.x + xv.y * wv.y + xv.z * wv.z + xv.w * wv.w;
    }
#pragma unroll
    for (int off = 16; off; off >>= 1)
#pragma unroll
        for (int k = 0; k < 8; ++k) p[k] += __shfl_down(p[k], off, 32);

    if (lane == 0) {
        float s = 0.f, d = 0.f;
#pragma unroll
        for (int k = 0; k < 8; ++k) {
            h1[(size_t)node * 8 + k] = p[k];
            s += p[k] * av[k];
            d += p[k] * av[8 + k];
        }
        as1[node] = s;
        ad1[node] = d;
    }
}

// ============================ bucket-sort CSR build (atomic-free reservation) ============================

// pass 1a: per-block coarse histogram -> gmat[block][NB] (no global atomics)
__global__ __launch_bounds__(256) void p1a(const int* __restrict__ dst, int* __restrict__ gmat,
                                           int E, int NB)
{
    __shared__ int h[MAXNB];
    for (int i = threadIdx.x; i < NB; i += 256) h[i] = 0;
    __syncthreads();
    int base = blockIdx.x * CHUNK;
    int end = base + CHUNK; if (end > E) end = E;
    for (int i = base + threadIdx.x; i < end; i += 256)
        atomicAdd(&h[dst[i] >> CSHIFT], 1);
    __syncthreads();
    int* row = gmat + (size_t)blockIdx.x * NB;
    for (int i = threadIdx.x; i < NB; i += 256) row[i] = h[i];
}

// matrix scan: cptr[b] = global bucket base; pbase[k][b] = per-block base. Coalesced rows.
__global__ __launch_bounds__(512) void pscanM(const int* __restrict__ gmat, int* __restrict__ pbase,
    int* __restrict__ cptr, int* __restrict__ row_ptr, int NBLK, int NB, int n, int E)
{
    __shared__ int wsum[8];
    int b = threadIdx.x;
    int colsum = 0;
    if (b < NB)
        for (int k = 0; k < NBLK; ++k) colsum += gmat[(size_t)k * NB + b];
    // block exclusive scan over 512 threads
    int lane = b & 63, w = b >> 6;
    int s = colsum;
#pragma unroll
    for (int off = 1; off < 64; off <<= 1) {
        int t = __shfl_up(s, off, 64);
        if (lane >= off) s += t;
    }
    if (lane == 63) wsum[w] = s;
    __syncthreads();
    if (b == 0) { int a = 0; for (int i = 0; i < 8; ++i) { int t = wsum[i]; wsum[i] = a; a += t; } }
    __syncthreads();
    int excl = s - colsum + wsum[w];
    if (b < NB) cptr[b] = excl;
    if (b == 0) { cptr[NB] = E; row_ptr[n] = E; }
    if (b < NB) {
        int run = excl;
        for (int k = 0; k < NBLK; ++k) {
            pbase[(size_t)k * NB + b] = run;
            run += gmat[(size_t)k * NB + b];
        }
    }
}

// pass 1b: partition edges into coarse buckets (reads per-block bases; 1 LDS atomic/edge)
__global__ __launch_bounds__(256) void p1bM(const int* __restrict__ src, const int* __restrict__ dst,
    const int* __restrict__ pbase, unsigned* __restrict__ stage, int E, int NB)
{
    __shared__ int bbase[MAXNB], ccur[MAXNB];
    const int* prow = pbase + (size_t)blockIdx.x * NB;
    for (int i = threadIdx.x; i < NB; i += 256) { bbase[i] = prow[i]; ccur[i] = 0; }
    __syncthreads();
    int base = blockIdx.x * CHUNK;
    int end = base + CHUNK; if (end > E) end = E;
    for (int i = base + threadIdx.x; i < end; i += 256) {
        int d = dst[i];
        int b = d >> CSHIFT;
        int off = atomicAdd(&ccur[b], 1);
        stage[bbase[b] + off] = ((unsigned)(d & ((1 << CSHIFT) - 1)) << 17) | (unsigned)src[i];
    }
}

// pass 2: per-bucket fine counting-sort -> colsrc + row_ptr
__global__ __launch_bounds__(256) void p2(const unsigned* __restrict__ stage,
    const int* __restrict__ cptr, int* __restrict__ colsrc, int* __restrict__ row_ptr, int n)
{
    int b = blockIdx.x;
    int nbase = b << CSHIFT;
    int NN = n - nbase; if (NN > 256) NN = 256;
    __shared__ int h[256], bps[256], cc[256];
    __shared__ int wsum[4];
    int tid = threadIdx.x;
    h[tid] = 0; cc[tid] = 0;
    __syncthreads();
    int s0 = cptr[b], s1 = cptr[b + 1];
    for (int i = s0 + tid; i < s1; i += 256)
        atomicAdd(&h[stage[i] >> 17], 1);
    __syncthreads();
    int v = h[tid];
    int lane = tid & 63, w = tid >> 6;
    int sc = v;
#pragma unroll
    for (int off = 1; off < 64; off <<= 1) {
        int t = __shfl_up(sc, off, 64);
        if (lane >= off) sc += t;
    }
    if (lane == 63) wsum[w] = sc;
    __syncthreads();
    if (tid == 0) { int a = 0; for (int i = 0; i < 4; ++i) { int t = wsum[i]; wsum[i] = a; a += t; } }
    __syncthreads();
    int excl = sc - v + wsum[w];
    bps[tid] = s0 + excl;
    if (tid < NN) row_ptr[nbase + tid] = s0 + excl;
    __syncthreads();
    for (int i = s0 + tid; i < s1; i += 256) {
        unsigned p = stage[i];
        int f = p >> 17;
        int off = atomicAdd(&cc[f], 1);
        colsrc[bps[f] + off] = (int)(p & 0x1FFFFu);
    }
}

// ============================ gathers ============================

// Layer 1 gather, fused with layer-2 node transform:
// h' = relu(acc/denom + b1);  g = h'@W2;  as2/ad2 = g.a2
__global__ __launch_bounds__(256) void k_gather8f(const int* __restrict__ row_ptr,
    const int* __restrict__ colsrc, const float* __restrict__ as, const float* __restrict__ ad,
    const float* __restrict__ feat, const float* __restrict__ b1,
    const float* __restrict__ W2, const float* __restrict__ a2s, const float* __restrict__ a2d,
    float* __restrict__ g, float* __restrict__ as2, float* __restrict__ ad2, int n)
{
    __shared__ float w2s[128], a2sv[16], a2dv[16], b1v[8];
    if (threadIdx.x < 128) w2s[threadIdx.x] = W2[threadIdx.x];
    else if (threadIdx.x < 144) a2sv[threadIdx.x - 128] = a2s[threadIdx.x - 128];
    else if (threadIdx.x < 160) a2dv[threadIdx.x - 144] = a2d[threadIdx.x - 144];
    else if (threadIdx.x < 168) b1v[threadIdx.x - 160] = b1[threadIdx.x - 160];
    __syncthreads();

    int node = (blockIdx.x * 256 + threadIdx.x) >> 6;
    int lane = threadIdx.x & 63;
    if (node >= n) return;
    int start = row_ptr[node], end = row_ptr[node + 1];
    float adn = ad[node];
    float wsum = 0.f;
    float acc[8];
#pragma unroll
    for (int k = 0; k < 8; ++k) acc[k] = 0.f;

    for (int i = start + lane; i < end; i += 64) {
        int s = colsrc[i];
        float t = as[s] + adn;
        float w = __expf(t > 0.f ? t : NEG * t);  // max-shift skipped: |t| small, exact ratio
        wsum += w;
        const float4* fs4 = (const float4*)(feat + (size_t)s * 8);
        float4 f0 = fs4[0], f1 = fs4[1];
        acc[0] += w * f0.x; acc[1] += w * f0.y; acc[2] += w * f0.z; acc[3] += w * f0.w;
        acc[4] += w * f1.x; acc[5] += w * f1.y; acc[6] += w * f1.z; acc[7] += w * f1.w;
    }
#pragma unroll
    for (int off = 32; off; off >>= 1) {
        wsum += __shfl_xor(wsum, off, 64);
#pragma unroll
        for (int k = 0; k < 8; ++k) acc[k] += __shfl_xor(acc[k], off, 64);
    }
    float inv = wsum > 0.f ? 1.f / wsum : 0.f;
    float h[8];
#pragma unroll
    for (int k = 0; k < 8; ++k) {
        float v = acc[k] * inv + b1v[k];
        h[k] = v > 0.f ? v : 0.f;
    }
    // lanes 0..15: one output class each
    if (lane < 16) {
        float gv = 0.f;
#pragma unroll
        for (int k = 0; k < 8; ++k) gv += h[k] * w2s[k * 16 + lane];
        g[(size_t)node * 16 + lane] = gv;
        float ps = gv * a2sv[lane];
        float pd = gv * a2dv[lane];
#pragma unroll
        for (int off = 8; off; off >>= 1) {
            ps += __shfl_xor(ps, off, 16);
            pd += __shfl_xor(pd, off, 16);
        }
        if (lane == 0) { as2[node] = ps; ad2[node] = pd; }
    }
}

// Layer 2 gather with fused log_softmax
__global__ __launch_bounds__(256) void k_gather16(const int* __restrict__ row_ptr,
    const int* __restrict__ colsrc, const float* __restrict__ as, const float* __restrict__ ad,
    const float* __restrict__ feat, const float* __restrict__ bias, float* __restrict__ outp, int n)
{
    int node = (blockIdx.x * 256 + threadIdx.x) >> 6;
    int lane = threadIdx.x & 63;
    if (node >= n) return;
    int start = row_ptr[node], end = row_ptr[node + 1];
    float adn = ad[node];
    float wsum = 0.f;
    float acc[16];
#pragma unroll
    for (int k = 0; k < 16; ++k) acc[k] = 0.f;

    for (int i = start + lane; i < end; i += 64) {
        int s = colsrc[i];
        float t = as[s] + adn;
        float w = __expf(t > 0.f ? t : NEG * t);
        wsum += w;
        const float4* fs4 = (const float4*)(feat + (size_t)s * 16);
#pragma unroll
        for (int q = 0; q < 4; ++q) {
            float4 fv = fs4[q];
            acc[4 * q + 0] += w * fv.x;
            acc[4 * q + 1] += w * fv.y;
            acc[4 * q + 2] += w * fv.z;
            acc[4 * q + 3] += w * fv.w;
        }
    }
#pragma unroll
    for (int off = 32; off; off >>= 1) {
        wsum += __shfl_xor(wsum, off, 64);
#pragma unroll
        for (int k = 0; k < 16; ++k) acc[k] += __shfl_xor(acc[k], off, 64);
    }
    float inv = wsum > 0.f ? 1.f / wsum : 0.f;
    float o[16], m = -1e30f;
#pragma unroll
    for (int c = 0; c < 16; ++c) {
        o[c] = acc[c] * inv + bias[c];
        m = fmaxf(m, o[c]);
    }
    float se = 0.f;
#pragma unroll
    for (int c = 0; c < 16; ++c) se += __expf(o[c] - m);
    float l = m + __logf(se);
    if (lane < 16) outp[(size_t)node * 16 + lane] = o[lane] - l;
}

// ============================ fallback tier 1: legacy CSR ============================

__global__ __launch_bounds__(256) void k_hist(const int* __restrict__ dst, int* __restrict__ deg, int E)
{
    int e = blockIdx.x * 256 + threadIdx.x;
    if (e < E) atomicAdd(deg + dst[e], 1);
}

__global__ __launch_bounds__(1024) void k_scan(const int* __restrict__ deg, int* __restrict__ row_ptr,
                                               int n, int E)
{
    const int T = 1024;
    int tid = threadIdx.x;
    int chunk = (n + T - 1) / T;
    int base = tid * chunk;
    int s = 0;
    for (int j = 0; j < chunk; ++j) {
        int idx = base + j;
        if (idx < n) s += deg[idx];
    }
    int lane = tid & 63, w = tid >> 6;
    int v = s;
#pragma unroll
    for (int off = 1; off < 64; off <<= 1) {
        int t = __shfl_up(v, off, 64);
        if (lane >= off) v += t;
    }
    __shared__ int wsum[16];
    if (lane == 63) wsum[w] = v;
    __syncthreads();
    if (tid == 0) {
        int a = 0;
#pragma unroll
        for (int i = 0; i < 16; ++i) { int t = wsum[i]; wsum[i] = a; a += t; }
    }
    __syncthreads();
    int run = v - s + wsum[w];
    for (int j = 0; j < chunk; ++j) {
        int idx = base + j;
        if (idx < n) { row_ptr[idx] = run; run += deg[idx]; }
    }
    if (tid == 0) row_ptr[n] = E;
}

__global__ __launch_bounds__(256) void k_scatter(const int* __restrict__ src, const int* __restrict__ dst,
    int* __restrict__ cursor, int* __restrict__ colsrc, int E)
{
    int e = blockIdx.x * 256 + threadIdx.x;
    if (e >= E) return;
    int d = dst[e];
    int pos = atomicAdd(cursor + d, 1);
    colsrc[pos] = src[e];
}

// ============================ fallback tier 2: atomic path ============================

template <int F>
__global__ __launch_bounds__(256) void k_edge(const int* __restrict__ src, const int* __restrict__ dst,
    const float* __restrict__ as, const float* __restrict__ ad, const float* __restrict__ feat,
    float* __restrict__ denom, float* __restrict__ acc, int E)
{
    int e = blockIdx.x * 256 + threadIdx.x;
    if (e >= E) return;
    int s = src[e], d = dst[e];
    float t = as[s] + ad[d];
    float w = __expf(t > 0.f ? t : NEG * t);
    atomicAdd(denom + d, w);
    const float* fs = feat + (size_t)s * F;
    float* ac = acc + (size_t)d * F;
#pragma unroll
    for (int k = 0; k < F; ++k) atomicAdd(ac + k, w * fs[k]);
}

__global__ __launch_bounds__(256) void k3_node(const float* __restrict__ denom1,
    const float* __restrict__ acc1, const float* __restrict__ b1,
    const float* __restrict__ W2, const float* __restrict__ a2s, const float* __restrict__ a2d,
    float* __restrict__ g, float* __restrict__ as2, float* __restrict__ ad2, int n)
{
    __shared__ float w2[128];
    __shared__ float aa[32];
    __shared__ float bb[8];
    if (threadIdx.x < 128) w2[threadIdx.x] = W2[threadIdx.x];
    if (threadIdx.x >= 128 && threadIdx.x < 144) aa[threadIdx.x - 128] = a2s[threadIdx.x - 128];
    if (threadIdx.x >= 144 && threadIdx.x < 160) aa[16 + threadIdx.x - 144] = a2d[threadIdx.x - 144];
    if (threadIdx.x >= 160 && threadIdx.x < 168) bb[threadIdx.x - 160] = b1[threadIdx.x - 160];
    __syncthreads();

    int node = blockIdx.x * 256 + threadIdx.x;
    if (node >= n) return;
    float dn = denom1[node];
    float inv = dn > 0.f ? 1.f / dn : 0.f;
    float h[8];
#pragma unroll
    for (int k = 0; k < 8; ++k) {
        float v = acc1[(size_t)node * 8 + k] * inv + bb[k];
        h[k] = v > 0.f ? v : 0.f;
    }
    float s = 0.f, dd = 0.f;
#pragma unroll
    for (int c = 0; c < 16; ++c) {
        float gv = 0.f;
#pragma unroll
        for (int k = 0; k < 8; ++k) gv += h[k] * w2[k * 16 + c];
        g[(size_t)node * 16 + c] = gv;
        s += gv * aa[c];
        dd += gv * aa[16 + c];
    }
    as2[node] = s;
    ad2[node] = dd;
}

__global__ __launch_bounds__(256) void k5_final(const float* __restrict__ denom2,
    const float* __restrict__ acc2, const float* __restrict__ b2, float* __restrict__ out, int n)
{
    __shared__ float bb[16];
    if (threadIdx.x < 16) bb[threadIdx.x] = b2[threadIdx.x];
    __syncthreads();

    int node = blockIdx.x * 256 + threadIdx.x;
    if (node >= n) return;
    float dn = denom2[node];
    float inv = dn > 0.f ? 1.f / dn : 0.f;
    float o[16];
    float m = -1e30f;
#pragma unroll
    for (int c = 0; c < 16; ++c) {
        o[c] = acc2[(size_t)node * 16 + c] * inv + bb[c];
        m = fmaxf(m, o[c]);
    }
    float se = 0.f;
#pragma unroll
    for (int c = 0; c < 16; ++c) {
        o[c] -= m;
        se += __expf(o[c]);
    }
    float l = __logf(se);
#pragma unroll
    for (int c = 0; c < 16; ++c) out[(size_t)node * 16 + c] = o[c] - l;
}

// ============================ launch ============================

static inline char* align256(char* p) {
    return (char*)(((uintptr_t)p + 255) & ~(uintptr_t)255);
}

extern "C" void kernel_launch(void* const* d_in, const int* in_sizes, int n_in,
                              void* d_out, int out_size, void* d_ws, size_t ws_size,
                              hipStream_t stream)
{
    const float* x    = (const float*)d_in[0];
    const int*   eidx = (const int*)d_in[1];
    const float* W1   = (const float*)d_in[2];
    const float* a1s  = (const float*)d_in[3];
    const float* a1d  = (const float*)d_in[4];
    const float* b1   = (const float*)d_in[5];
    const float* W2   = (const float*)d_in[6];
    const float* a2s  = (const float*)d_in[7];
    const float* a2d  = (const float*)d_in[8];
    const float* b2   = (const float*)d_in[9];
    float* out = (float*)d_out;

    const int n = in_sizes[0] / 128;
    const int E = in_sizes[1] / 2;
    const int* src = eidx;
    const int* dst = eidx + E;
    const int NB = (n + 255) >> CSHIFT;
    const int NBLK = (E + CHUNK - 1) / CHUNK;

    // ---- tier-0: matrix-scan bucket-sort CSR ----
    {
        char* p = (char*)d_ws;
        char* p0 = p;
        unsigned* stage = (unsigned*)p;  p = align256(p + (size_t)E * 4);
        int* colsrc  = (int*)p;          p = align256(p + (size_t)E * 4);
        int* gmat    = (int*)p;          p = align256(p + (size_t)NBLK * NB * 4);
        int* pbase   = (int*)p;          p = align256(p + (size_t)NBLK * NB * 4);
        int* cptr    = (int*)p;          p = align256(p + (size_t)(NB + 1) * 4);
        int* row_ptr = (int*)p;          p = align256(p + (size_t)(n + 1) * 4);
        float* h1    = (float*)p;        p = align256(p + (size_t)8 * n * 4);
        float* g     = (float*)p;        p = align256(p + (size_t)16 * n * 4);
        float* as1   = (float*)p;        p = align256(p + (size_t)n * 4);
        float* ad1   = (float*)p;        p = align256(p + (size_t)n * 4);
        float* as2   = (float*)p;        p = align256(p + (size_t)n * 4);
        float* ad2   = (float*)p;        p = align256(p + (size_t)n * 4);
        size_t needed = (size_t)(p - p0);

        if (n <= 131072 && NB <= MAXNB && ws_size >= needed) {
            k1_node<<<(n + 7) / 8, 256, 0, stream>>>(x, W1, a1s, a1d, h1, as1, ad1, n);

            p1a<<<NBLK, 256, 0, stream>>>(dst, gmat, E, NB);
            pscanM<<<1, 512, 0, stream>>>(gmat, pbase, cptr, row_ptr, NBLK, NB, n, E);
            p1bM<<<NBLK, 256, 0, stream>>>(src, dst, pbase, stage, E, NB);
            p2<<<NB, 256, 0, stream>>>(stage, cptr, colsrc, row_ptr, n);

            const int gblocks = (n * 64 + 255) / 256;
            k_gather8f<<<gblocks, 256, 0, stream>>>(row_ptr, colsrc, as1, ad1, h1,
                                                    b1, W2, a2s, a2d, g, as2, ad2, n);
            k_gather16<<<gblocks, 256, 0, stream>>>(row_ptr, colsrc, as2, ad2, g, b2, out, n);
            return;
        }
    }

    // ---- tier-1: legacy CSR (atomic scatter) ----
    {
        size_t int_elems = (size_t)E + n + n + (n + 16);
        size_t flt_elems = (size_t)44 * n;
        size_t needed = 4 * (int_elems + flt_elems);
        if (ws_size >= needed) {
            char* p = (char*)d_ws;
            int* colsrc  = (int*)p;               p += (size_t)E * 4;
            int* deg     = (int*)p;               p += (size_t)n * 4;
            int* cursor  = (int*)p;               p += (size_t)n * 4;
            int* row_ptr = (int*)p;               p += (size_t)(n + 16) * 4;
            float* h1    = (float*)p;             p += (size_t)8 * n * 4;
            float* g     = (float*)p;             p += (size_t)16 * n * 4;
            float* as1   = (float*)p;             p += (size_t)n * 4;
            float* ad1   = (float*)p;             p += (size_t)n * 4;
            float* as2   = (float*)p;             p += (size_t)n * 4;
            float* ad2   = (float*)p;

            hipMemsetAsync(deg, 0, (size_t)n * 4, stream);
            k1_node<<<(n + 7) / 8, 256, 0, stream>>>(x, W1, a1s, a1d, h1, as1, ad1, n);
            k_hist<<<(E + 255) / 256, 256, 0, stream>>>(dst, deg, E);
            k_scan<<<1, 1024, 0, stream>>>(deg, row_ptr, n, E);
            hipMemcpyAsync(cursor, row_ptr, (size_t)n * 4, hipMemcpyDeviceToDevice, stream);
            k_scatter<<<(E + 255) / 256, 256, 0, stream>>>(src, dst, cursor, colsrc, E);

            const int gblocks = (n * 64 + 255) / 256;
            k_gather8f<<<gblocks, 256, 0, stream>>>(row_ptr, colsrc, as1, ad1, h1,
                                                    b1, W2, a2s, a2d, g, as2, ad2, n);
            k_gather16<<<gblocks, 256, 0, stream>>>(row_ptr, colsrc, as2, ad2, g, b2, out, n);
            return;
        }
    }

    // ---- tier-2: pure atomic path ----
    {
        float* ws     = (float*)d_ws;
        float* denom1 = ws;
        float* acc1   = ws + (size_t)n;
        float* denom2 = ws + (size_t)9 * n;
        float* acc2   = ws + (size_t)10 * n;
        float* h1     = ws + (size_t)26 * n;
        float* as1    = ws + (size_t)34 * n;
        float* ad1    = ws + (size_t)35 * n;
        float* g      = ws + (size_t)36 * n;
        float* as2    = ws + (size_t)52 * n;
        float* ad2    = ws + (size_t)53 * n;

        hipMemsetAsync(ws, 0, (size_t)26 * n * sizeof(float), stream);
        k1_node<<<(n + 7) / 8, 256, 0, stream>>>(x, W1, a1s, a1d, h1, as1, ad1, n);
        k_edge<8><<<(E + 255) / 256, 256, 0, stream>>>(src, dst, as1, ad1, h1, denom1, acc1, E);
        k3_node<<<(n + 255) / 256, 256, 0, stream>>>(denom1, acc1, b1, W2, a2s, a2d, g, as2, ad2, n);
        k_edge<16><<<(E + 255) / 256, 256, 0, stream>>>(src, dst, as2, ad2, g, denom2, acc2, E);
        k5_final<<<(n + 255) / 256, 256, 0, stream>>>(denom2, acc2, b2, out, n);
    }
}

// Round 9
// 384.689 us; speedup vs baseline: 1.6419x; 1.6419x over previous
//
#include <hip/hip_runtime.h>
#include <math.h>
#include <stdint.h>

#define NEG 0.2f
#define CSHIFT 8
#define MAXNB 512          // supports n <= 131072 (17-bit src pack)
#define CHUNK 2048

// ============================ node transform ============================

__global__ __launch_bounds__(256) void k1_node(const float* __restrict__ x,
    const float* __restrict__ W1, const float* __restrict__ a1s, const float* __restrict__ a1d,
    float* __restrict__ h1, float* __restrict__ as1, float* __restrict__ ad1, int n)
{
    __shared__ float wt[8 * 128];
    __shared__ float av[16];
    for (int i = threadIdx.x; i < 1024; i += 256) {
        int r = i >> 3, k = i & 7;
        wt[k * 128 + r] = W1[i];
    }
    if (threadIdx.x < 8)        av[threadIdx.x] = a1s[threadIdx.x];
    else if (threadIdx.x < 16)  av[threadIdx.x] = a1d[threadIdx.x - 8];
    __syncthreads();

    int lane = threadIdx.x & 31;
    int node = blockIdx.x * 8 + (threadIdx.x >> 5);
    if (node >= n) return;

    float4 xv = ((const float4*)(x + (size_t)node * 128))[lane];
    float p[8];
#pragma unroll
    for (int k = 0; k < 8; ++k) {
        float4 wv = ((const float4*)(wt + k * 128))[lane];
        p[k] = xv.x * wv.x + xv.y * wv.y + xv.z * wv.z + xv.w * wv.w;
    }
#pragma unroll
    for (int off = 16; off; off >>= 1)
#pragma unroll
        for (int k = 0; k < 8; ++k) p[k] += __shfl_down(p[k], off, 32);

    if (lane == 0) {
        float s = 0.f, d = 0.f;
#pragma unroll
        for (int k = 0; k < 8; ++k) {
            h1[(size_t)node * 8 + k] = p[k];
            s += p[k] * av[k];
            d += p[k] * av[8 + k];
        }
        as1[node] = s;
        ad1[node] = d;
    }
}

// ============================ bucket-sort CSR build (all-parallel, atomic-free) ============================

// pass 1a: per-block coarse histogram -> gmat[block][NB]
__global__ __launch_bounds__(256) void p1a(const int* __restrict__ dst, int* __restrict__ gmat,
                                           int E, int NB)
{
    __shared__ int h[MAXNB];
    for (int i = threadIdx.x; i < NB; i += 256) h[i] = 0;
    __syncthreads();
    int base = blockIdx.x * CHUNK;
    int end = base + CHUNK; if (end > E) end = E;
    for (int i = base + threadIdx.x; i < end; i += 256)
        atomicAdd(&h[dst[i] >> CSHIFT], 1);
    __syncthreads();
    int* row = gmat + (size_t)blockIdx.x * NB;
    for (int i = threadIdx.x; i < NB; i += 256) row[i] = h[i];
}

// per-bucket column prefix: pbaseRel[k][b] = exclusive prefix of gmat[0..k)[b]; total[b] = column sum
__global__ __launch_bounds__(256) void pcol(const int* __restrict__ gmat, int* __restrict__ pbaseRel,
    int* __restrict__ total, int NBLK, int NB)
{
    __shared__ int wsum[4];
    int b = blockIdx.x;
    int tid = threadIdx.x;
    int chunk = (NBLK + 255) >> 8;
    int k0 = tid * chunk;
    int s = 0;
    for (int j = 0; j < chunk; ++j) {
        int k = k0 + j;
        if (k < NBLK) s += gmat[(size_t)k * NB + b];
    }
    int lane = tid & 63, w = tid >> 6;
    int sc = s;
#pragma unroll
    for (int off = 1; off < 64; off <<= 1) {
        int t = __shfl_up(sc, off, 64);
        if (lane >= off) sc += t;
    }
    if (lane == 63) wsum[w] = sc;
    __syncthreads();
    if (tid == 0) { int a = 0; for (int i = 0; i < 4; ++i) { int t = wsum[i]; wsum[i] = a; a += t; } }
    __syncthreads();
    int run = sc - s + wsum[w];   // exclusive prefix for this thread's chunk
    for (int j = 0; j < chunk; ++j) {
        int k = k0 + j;
        if (k < NBLK) {
            int gv = gmat[(size_t)k * NB + b];
            pbaseRel[(size_t)k * NB + b] = run;
            run += gv;
        }
    }
    if (tid == 255) total[b] = run;  // grand total of column b
}

// scan bucket totals -> cptr (single block, NB <= 512; few microseconds)
__global__ __launch_bounds__(512) void ptot(const int* __restrict__ total, int* __restrict__ cptr,
                                            int* __restrict__ row_ptr, int NB, int n, int E)
{
    __shared__ int wsum[8];
    int b = threadIdx.x;
    int v = b < NB ? total[b] : 0;
    int lane = b & 63, w = b >> 6;
    int s = v;
#pragma unroll
    for (int off = 1; off < 64; off <<= 1) {
        int t = __shfl_up(s, off, 64);
        if (lane >= off) s += t;
    }
    if (lane == 63) wsum[w] = s;
    __syncthreads();
    if (b == 0) { int a = 0; for (int i = 0; i < 8; ++i) { int t = wsum[i]; wsum[i] = a; a += t; } }
    __syncthreads();
    int excl = s - v + wsum[w];
    if (b < NB) cptr[b] = excl;
    if (b == 0) { cptr[NB] = E; row_ptr[n] = E; }
}

// pass 1b: partition edges into coarse buckets; base = cptr[b] + pbaseRel[blk][b]
__global__ __launch_bounds__(256) void p1bM(const int* __restrict__ src, const int* __restrict__ dst,
    const int* __restrict__ cptr, const int* __restrict__ pbaseRel, unsigned* __restrict__ stage,
    int E, int NB)
{
    __shared__ int bbase[MAXNB], ccur[MAXNB];
    const int* prow = pbaseRel + (size_t)blockIdx.x * NB;
    for (int i = threadIdx.x; i < NB; i += 256) { bbase[i] = cptr[i] + prow[i]; ccur[i] = 0; }
    __syncthreads();
    int base = blockIdx.x * CHUNK;
    int end = base + CHUNK; if (end > E) end = E;
    for (int i = base + threadIdx.x; i < end; i += 256) {
        int d = dst[i];
        int b = d >> CSHIFT;
        int off = atomicAdd(&ccur[b], 1);
        stage[bbase[b] + off] = ((unsigned)(d & ((1 << CSHIFT) - 1)) << 17) | (unsigned)src[i];
    }
}

// pass 2: per-bucket fine counting-sort -> colsrc + row_ptr (512 threads for latency hiding)
__global__ __launch_bounds__(512) void p2(const unsigned* __restrict__ stage,
    const int* __restrict__ cptr, int* __restrict__ colsrc, int* __restrict__ row_ptr, int n)
{
    int b = blockIdx.x;
    int nbase = b << CSHIFT;
    int NN = n - nbase; if (NN > 256) NN = 256;
    __shared__ int h[256], bps[256], cc[256];
    __shared__ int wsum[4];
    int tid = threadIdx.x;
    for (int i = tid; i < 256; i += 512) { h[i] = 0; cc[i] = 0; }
    __syncthreads();
    int s0 = cptr[b], s1 = cptr[b + 1];
    for (int i = s0 + tid; i < s1; i += 512)
        atomicAdd(&h[stage[i] >> 17], 1);
    __syncthreads();
    int v = 0, sc = 0;
    int lane = tid & 63, w = tid >> 6;
    if (tid < 256) {
        v = h[tid];
        sc = v;
#pragma unroll
        for (int off = 1; off < 64; off <<= 1) {
            int t = __shfl_up(sc, off, 64);
            if (lane >= off) sc += t;
        }
        if (lane == 63) wsum[w] = sc;
    }
    __syncthreads();
    if (tid == 0) { int a = 0; for (int i = 0; i < 4; ++i) { int t = wsum[i]; wsum[i] = a; a += t; } }
    __syncthreads();
    if (tid < 256) {
        int excl = sc - v + wsum[w];
        bps[tid] = s0 + excl;
        if (tid < NN) row_ptr[nbase + tid] = s0 + excl;
    }
    __syncthreads();
    for (int i = s0 + tid; i < s1; i += 512) {
        unsigned p = stage[i];
        int f = p >> 17;
        int off = atomicAdd(&cc[f], 1);
        colsrc[bps[f] + off] = (int)(p & 0x1FFFFu);
    }
}

// ============================ gathers ============================

// Layer 1 gather, fused with layer-2 node transform
__global__ __launch_bounds__(256) void k_gather8f(const int* __restrict__ row_ptr,
    const int* __restrict__ colsrc, const float* __restrict__ as, const float* __restrict__ ad,
    const float* __restrict__ feat, const float* __restrict__ b1,
    const float* __restrict__ W2, const float* __restrict__ a2s, const float* __restrict__ a2d,
    float* __restrict__ g, float* __restrict__ as2, float* __restrict__ ad2, int n)
{
    __shared__ float w2s[128], a2sv[16], a2dv[16], b1v[8];
    if (threadIdx.x < 128) w2s[threadIdx.x] = W2[threadIdx.x];
    else if (threadIdx.x < 144) a2sv[threadIdx.x - 128] = a2s[threadIdx.x - 128];
    else if (threadIdx.x < 160) a2dv[threadIdx.x - 144] = a2d[threadIdx.x - 144];
    else if (threadIdx.x < 168) b1v[threadIdx.x - 160] = b1[threadIdx.x - 160];
    __syncthreads();

    int node = (blockIdx.x * 256 + threadIdx.x) >> 6;
    int lane = threadIdx.x & 63;
    if (node >= n) return;
    int start = row_ptr[node], end = row_ptr[node + 1];
    float adn = ad[node];
    float wsum = 0.f;
    float acc[8];
#pragma unroll
    for (int k = 0; k < 8; ++k) acc[k] = 0.f;

    for (int i = start + lane; i < end; i += 64) {
        int s = colsrc[i];
        float t = as[s] + adn;
        float w = __expf(t > 0.f ? t : NEG * t);  // max-shift skipped: |t| small, exact ratio
        wsum += w;
        const float4* fs4 = (const float4*)(feat + (size_t)s * 8);
        float4 f0 = fs4[0], f1 = fs4[1];
        acc[0] += w * f0.x; acc[1] += w * f0.y; acc[2] += w * f0.z; acc[3] += w * f0.w;
        acc[4] += w * f1.x; acc[5] += w * f1.y; acc[6] += w * f1.z; acc[7] += w * f1.w;
    }
#pragma unroll
    for (int off = 32; off; off >>= 1) {
        wsum += __shfl_xor(wsum, off, 64);
#pragma unroll
        for (int k = 0; k < 8; ++k) acc[k] += __shfl_xor(acc[k], off, 64);
    }
    float inv = wsum > 0.f ? 1.f / wsum : 0.f;
    float h[8];
#pragma unroll
    for (int k = 0; k < 8; ++k) {
        float v = acc[k] * inv + b1v[k];
        h[k] = v > 0.f ? v : 0.f;
    }
    if (lane < 16) {
        float gv = 0.f;
#pragma unroll
        for (int k = 0; k < 8; ++k) gv += h[k] * w2s[k * 16 + lane];
        g[(size_t)node * 16 + lane] = gv;
        float ps = gv * a2sv[lane];
        float pd = gv * a2dv[lane];
#pragma unroll
        for (int off = 8; off; off >>= 1) {
            ps += __shfl_xor(ps, off, 16);
            pd += __shfl_xor(pd, off, 16);
        }
        if (lane == 0) { as2[node] = ps; ad2[node] = pd; }
    }
}

// Layer 2 gather with fused log_softmax
__global__ __launch_bounds__(256) void k_gather16(const int* __restrict__ row_ptr,
    const int* __restrict__ colsrc, const float* __restrict__ as, const float* __restrict__ ad,
    const float* __restrict__ feat, const float* __restrict__ bias, float* __restrict__ outp, int n)
{
    int node = (blockIdx.x * 256 + threadIdx.x) >> 6;
    int lane = threadIdx.x & 63;
    if (node >= n) return;
    int start = row_ptr[node], end = row_ptr[node + 1];
    float adn = ad[node];
    float wsum = 0.f;
    float acc[16];
#pragma unroll
    for (int k = 0; k < 16; ++k) acc[k] = 0.f;

    for (int i = start + lane; i < end; i += 64) {
        int s = colsrc[i];
        float t = as[s] + adn;
        float w = __expf(t > 0.f ? t : NEG * t);
        wsum += w;
        const float4* fs4 = (const float4*)(feat + (size_t)s * 16);
#pragma unroll
        for (int q = 0; q < 4; ++q) {
            float4 fv = fs4[q];
            acc[4 * q + 0] += w * fv.x;
            acc[4 * q + 1] += w * fv.y;
            acc[4 * q + 2] += w * fv.z;
            acc[4 * q + 3] += w * fv.w;
        }
    }
#pragma unroll
    for (int off = 32; off; off >>= 1) {
        wsum += __shfl_xor(wsum, off, 64);
#pragma unroll
        for (int k = 0; k < 16; ++k) acc[k] += __shfl_xor(acc[k], off, 64);
    }
    float inv = wsum > 0.f ? 1.f / wsum : 0.f;
    float o[16], m = -1e30f;
#pragma unroll
    for (int c = 0; c < 16; ++c) {
        o[c] = acc[c] * inv + bias[c];
        m = fmaxf(m, o[c]);
    }
    float se = 0.f;
#pragma unroll
    for (int c = 0; c < 16; ++c) se += __expf(o[c] - m);
    float l = m + __logf(se);
    if (lane < 16) outp[(size_t)node * 16 + lane] = o[lane] - l;
}

// ============================ fallback tier 1: legacy CSR ============================

__global__ __launch_bounds__(256) void k_hist(const int* __restrict__ dst, int* __restrict__ deg, int E)
{
    int e = blockIdx.x * 256 + threadIdx.x;
    if (e < E) atomicAdd(deg + dst[e], 1);
}

__global__ __launch_bounds__(1024) void k_scan(const int* __restrict__ deg, int* __restrict__ row_ptr,
                                               int n, int E)
{
    const int T = 1024;
    int tid = threadIdx.x;
    int chunk = (n + T - 1) / T;
    int base = tid * chunk;
    int s = 0;
    for (int j = 0; j < chunk; ++j) {
        int idx = base + j;
        if (idx < n) s += deg[idx];
    }
    int lane = tid & 63, w = tid >> 6;
    int v = s;
#pragma unroll
    for (int off = 1; off < 64; off <<= 1) {
        int t = __shfl_up(v, off, 64);
        if (lane >= off) v += t;
    }
    __shared__ int wsum[16];
    if (lane == 63) wsum[w] = v;
    __syncthreads();
    if (tid == 0) {
        int a = 0;
#pragma unroll
        for (int i = 0; i < 16; ++i) { int t = wsum[i]; wsum[i] = a; a += t; }
    }
    __syncthreads();
    int run = v - s + wsum[w];
    for (int j = 0; j < chunk; ++j) {
        int idx = base + j;
        if (idx < n) { row_ptr[idx] = run; run += deg[idx]; }
    }
    if (tid == 0) row_ptr[n] = E;
}

__global__ __launch_bounds__(256) void k_scatter(const int* __restrict__ src, const int* __restrict__ dst,
    int* __restrict__ cursor, int* __restrict__ colsrc, int E)
{
    int e = blockIdx.x * 256 + threadIdx.x;
    if (e >= E) return;
    int d = dst[e];
    int pos = atomicAdd(cursor + d, 1);
    colsrc[pos] = src[e];
}

// ============================ fallback tier 2: atomic path ============================

template <int F>
__global__ __launch_bounds__(256) void k_edge(const int* __restrict__ src, const int* __restrict__ dst,
    const float* __restrict__ as, const float* __restrict__ ad, const float* __restrict__ feat,
    float* __restrict__ denom, float* __restrict__ acc, int E)
{
    int e = blockIdx.x * 256 + threadIdx.x;
    if (e >= E) return;
    int s = src[e], d = dst[e];
    float t = as[s] + ad[d];
    float w = __expf(t > 0.f ? t : NEG * t);
    atomicAdd(denom + d, w);
    const float* fs = feat + (size_t)s * F;
    float* ac = acc + (size_t)d * F;
#pragma unroll
    for (int k = 0; k < F; ++k) atomicAdd(ac + k, w * fs[k]);
}

__global__ __launch_bounds__(256) void k3_node(const float* __restrict__ denom1,
    const float* __restrict__ acc1, const float* __restrict__ b1,
    const float* __restrict__ W2, const float* __restrict__ a2s, const float* __restrict__ a2d,
    float* __restrict__ g, float* __restrict__ as2, float* __restrict__ ad2, int n)
{
    __shared__ float w2[128];
    __shared__ float aa[32];
    __shared__ float bb[8];
    if (threadIdx.x < 128) w2[threadIdx.x] = W2[threadIdx.x];
    if (threadIdx.x >= 128 && threadIdx.x < 144) aa[threadIdx.x - 128] = a2s[threadIdx.x - 128];
    if (threadIdx.x >= 144 && threadIdx.x < 160) aa[16 + threadIdx.x - 144] = a2d[threadIdx.x - 144];
    if (threadIdx.x >= 160 && threadIdx.x < 168) bb[threadIdx.x - 160] = b1[threadIdx.x - 160];
    __syncthreads();

    int node = blockIdx.x * 256 + threadIdx.x;
    if (node >= n) return;
    float dn = denom1[node];
    float inv = dn > 0.f ? 1.f / dn : 0.f;
    float h[8];
#pragma unroll
    for (int k = 0; k < 8; ++k) {
        float v = acc1[(size_t)node * 8 + k] * inv + bb[k];
        h[k] = v > 0.f ? v : 0.f;
    }
    float s = 0.f, dd = 0.f;
#pragma unroll
    for (int c = 0; c < 16; ++c) {
        float gv = 0.f;
#pragma unroll
        for (int k = 0; k < 8; ++k) gv += h[k] * w2[k * 16 + c];
        g[(size_t)node * 16 + c] = gv;
        s += gv * aa[c];
        dd += gv * aa[16 + c];
    }
    as2[node] = s;
    ad2[node] = dd;
}

__global__ __launch_bounds__(256) void k5_final(const float* __restrict__ denom2,
    const float* __restrict__ acc2, const float* __restrict__ b2, float* __restrict__ out, int n)
{
    __shared__ float bb[16];
    if (threadIdx.x < 16) bb[threadIdx.x] = b2[threadIdx.x];
    __syncthreads();

    int node = blockIdx.x * 256 + threadIdx.x;
    if (node >= n) return;
    float dn = denom2[node];
    float inv = dn > 0.f ? 1.f / dn : 0.f;
    float o[16];
    float m = -1e30f;
#pragma unroll
    for (int c = 0; c < 16; ++c) {
        o[c] = acc2[(size_t)node * 16 + c] * inv + bb[c];
        m = fmaxf(m, o[c]);
    }
    float se = 0.f;
#pragma unroll
    for (int c = 0; c < 16; ++c) {
        o[c] -= m;
        se += __expf(o[c]);
    }
    float l = __logf(se);
#pragma unroll
    for (int c = 0; c < 16; ++c) out[(size_t)node * 16 + c] = o[c] - l;
}

// ============================ launch ============================

static inline char* align256(char* p) {
    return (char*)(((uintptr_t)p + 255) & ~(uintptr_t)255);
}

extern "C" void kernel_launch(void* const* d_in, const int* in_sizes, int n_in,
                              void* d_out, int out_size, void* d_ws, size_t ws_size,
                              hipStream_t stream)
{
    const float* x    = (const float*)d_in[0];
    const int*   eidx = (const int*)d_in[1];
    const float* W1   = (const float*)d_in[2];
    const float* a1s  = (const float*)d_in[3];
    const float* a1d  = (const float*)d_in[4];
    const float* b1   = (const float*)d_in[5];
    const float* W2   = (const float*)d_in[6];
    const float* a2s  = (const float*)d_in[7];
    const float* a2d  = (const float*)d_in[8];
    const float* b2   = (const float*)d_in[9];
    float* out = (float*)d_out;

    const int n = in_sizes[0] / 128;
    const int E = in_sizes[1] / 2;
    const int* src = eidx;
    const int* dst = eidx + E;
    const int NB = (n + 255) >> CSHIFT;
    const int NBLK = (E + CHUNK - 1) / CHUNK;

    // ---- tier-0: all-parallel bucket-sort CSR ----
    // gmat[NBLK][NB] and pbaseRel[NBLK][NB] are aliased INTO the colsrc region
    // (their lifetime ends before p2 writes colsrc): needs 2*NBLK*NB <= E.
    {
        char* p = (char*)d_ws;
        char* p0 = p;
        unsigned* stage = (unsigned*)p;  p = align256(p + (size_t)E * 4);
        int* colsrc  = (int*)p;          p = align256(p + (size_t)E * 4);
        int* total   = (int*)p;          p = align256(p + (size_t)NB * 4);
        int* cptr    = (int*)p;          p = align256(p + (size_t)(NB + 1) * 4);
        int* row_ptr = (int*)p;          p = align256(p + (size_t)(n + 1) * 4);
        float* h1    = (float*)p;        p = align256(p + (size_t)8 * n * 4);
        float* g     = (float*)p;        p = align256(p + (size_t)16 * n * 4);
        float* as1   = (float*)p;        p = align256(p + (size_t)n * 4);
        float* ad1   = (float*)p;        p = align256(p + (size_t)n * 4);
        float* as2   = (float*)p;        p = align256(p + (size_t)n * 4);
        float* ad2   = (float*)p;        p = align256(p + (size_t)n * 4);
        size_t needed = (size_t)(p - p0);

        int* gmat     = colsrc;                       // alias (dead before p2)
        int* pbaseRel = (int*)align256((char*)(colsrc + (size_t)NBLK * NB));

        bool alias_ok = ((size_t)2 * NBLK * NB + 64) <= (size_t)E;

        if (n <= 131072 && NB <= MAXNB && alias_ok && ws_size >= needed) {
            k1_node<<<(n + 7) / 8, 256, 0, stream>>>(x, W1, a1s, a1d, h1, as1, ad1, n);

            p1a<<<NBLK, 256, 0, stream>>>(dst, gmat, E, NB);
            pcol<<<NB, 256, 0, stream>>>(gmat, pbaseRel, total, NBLK, NB);
            ptot<<<1, 512, 0, stream>>>(total, cptr, row_ptr, NB, n, E);
            p1bM<<<NBLK, 256, 0, stream>>>(src, dst, cptr, pbaseRel, stage, E, NB);
            p2<<<NB, 512, 0, stream>>>(stage, cptr, colsrc, row_ptr, n);

            const int gblocks = (n * 64 + 255) / 256;
            k_gather8f<<<gblocks, 256, 0, stream>>>(row_ptr, colsrc, as1, ad1, h1,
                                                    b1, W2, a2s, a2d, g, as2, ad2, n);
            k_gather16<<<gblocks, 256, 0, stream>>>(row_ptr, colsrc, as2, ad2, g, b2, out, n);
            return;
        }
    }

    // ---- tier-1: legacy CSR (atomic scatter) ----
    {
        size_t int_elems = (size_t)E + n + n + (n + 16);
        size_t flt_elems = (size_t)44 * n;
        size_t needed = 4 * (int_elems + flt_elems);
        if (ws_size >= needed) {
            char* p = (char*)d_ws;
            int* colsrc  = (int*)p;               p += (size_t)E * 4;
            int* deg     = (int*)p;               p += (size_t)n * 4;
            int* cursor  = (int*)p;               p += (size_t)n * 4;
            int* row_ptr = (int*)p;               p += (size_t)(n + 16) * 4;
            float* h1    = (float*)p;             p += (size_t)8 * n * 4;
            float* g     = (float*)p;             p += (size_t)16 * n * 4;
            float* as1   = (float*)p;             p += (size_t)n * 4;
            float* ad1   = (float*)p;             p += (size_t)n * 4;
            float* as2   = (float*)p;             p += (size_t)n * 4;
            float* ad2   = (float*)p;

            hipMemsetAsync(deg, 0, (size_t)n * 4, stream);
            k1_node<<<(n + 7) / 8, 256, 0, stream>>>(x, W1, a1s, a1d, h1, as1, ad1, n);
            k_hist<<<(E + 255) / 256, 256, 0, stream>>>(dst, deg, E);
            k_scan<<<1, 1024, 0, stream>>>(deg, row_ptr, n, E);
            hipMemcpyAsync(cursor, row_ptr, (size_t)n * 4, hipMemcpyDeviceToDevice, stream);
            k_scatter<<<(E + 255) / 256, 256, 0, stream>>>(src, dst, cursor, colsrc, E);

            const int gblocks = (n * 64 + 255) / 256;
            k_gather8f<<<gblocks, 256, 0, stream>>>(row_ptr, colsrc, as1, ad1, h1,
                                                    b1, W2, a2s, a2d, g, as2, ad2, n);
            k_gather16<<<gblocks, 256, 0, stream>>>(row_ptr, colsrc, as2, ad2, g, b2, out, n);
            return;
        }
    }

    // ---- tier-2: pure atomic path ----
    {
        float* ws     = (float*)d_ws;
        float* denom1 = ws;
        float* acc1   = ws + (size_t)n;
        float* denom2 = ws + (size_t)9 * n;
        float* acc2   = ws + (size_t)10 * n;
        float* h1     = ws + (size_t)26 * n;
        float* as1    = ws + (size_t)34 * n;
        float* ad1    = ws + (size_t)35 * n;
        float* g      = ws + (size_t)36 * n;
        float* as2    = ws + (size_t)52 * n;
        float* ad2    = ws + (size_t)53 * n;

        hipMemsetAsync(ws, 0, (size_t)26 * n * sizeof(float), stream);
        k1_node<<<(n + 7) / 8, 256, 0, stream>>>(x, W1, a1s, a1d, h1, as1, ad1, n);
        k_edge<8><<<(E + 255) / 256, 256, 0, stream>>>(src, dst, as1, ad1, h1, denom1, acc1, E);
        k3_node<<<(n + 255) / 256, 256, 0, stream>>>(denom1, acc1, b1, W2, a2s, a2d, g, as2, ad2, n);
        k_edge<16><<<(E + 255) / 256, 256, 0, stream>>>(src, dst, as2, ad2, g, denom2, acc2, E);
        k5_final<<<(n + 255) / 256, 256, 0, stream>>>(denom2, acc2, b2, out, n);
    }
}